// Round 7
// baseline (746.236 us; speedup 1.0000x reference)
//
#include <hip/hip_runtime.h>

typedef unsigned short u16;
typedef unsigned int   u32;
typedef float  f32x2  __attribute__((ext_vector_type(2)));
typedef float  f32x4  __attribute__((ext_vector_type(4)));
typedef short  bf16x8 __attribute__((ext_vector_type(8)));
typedef u16    u16x4  __attribute__((ext_vector_type(4)));
typedef u32    u32x4  __attribute__((ext_vector_type(4)));

#define BQ 8
#define SQ 4096
#define DQ 1024
#define NQ 2048      // 2*D
#define MQ 32768     // B*S
#define KQ 1024
#define CCH 64       // chunks per sequence
#define TCH 64       // timesteps per chunk (CCH*TCH == SQ)
#define NT 16        // K-tiles (KQ/64)

__device__ __forceinline__ float bf2f(u16 u){
  union { u32 i; float f; } v; v.i = ((u32)u) << 16; return v.f;
}
__device__ __forceinline__ u16 f2bf(float f){
  union { float f; u32 i; } v; v.f = f;
  u32 r = v.i + 0x7fffu + ((v.i >> 16) & 1u);   // round-to-nearest-even
  return (u16)(r >> 16);
}

// a = 1 - sigmoid(gate) = sigmoid(-gate);  bv = sigmoid(gate) * g(hidden)
__device__ __forceinline__ void sig_ab(float gate, float hid, float& a, float& bv){
  float eg = __expf(gate);
  float a_ = __builtin_amdgcn_rcpf(1.f + eg);
  float z  = 1.f - a_;
  float eh = __expf(hid);
  float sg = eh * __builtin_amdgcn_rcpf(1.f + eh);
  float gval = (hid >= 0.f) ? (hid + 0.5f) : sg;
  a = a_; bv = z * gval;
}

__device__ __forceinline__ void gload_lds16(const u16* g, u16* l){
  __builtin_amdgcn_global_load_lds(
      (const __attribute__((address_space(1))) u32*)g,
      (__attribute__((address_space(3)))       u32*)l,
      16, 0, 0);
}

// ---------------- W transpose + bf16 cast: [L][K][N] f32 -> [L][N][K] bf16 ----
__global__ __launch_bounds__(256) void wt_cast(const float* __restrict__ W,
                                               u16* __restrict__ WT){
  __shared__ float t[64][65];
  const int l  = blockIdx.z;
  const int k0 = blockIdx.x << 6, n0 = blockIdx.y << 6;
  const float* Wl = W  + (size_t)l * KQ * NQ;
  u16*         Tl = WT + (size_t)l * NQ * KQ;
  const int c = threadIdx.x & 63, r4 = threadIdx.x >> 6;
  #pragma unroll
  for (int i = 0; i < 16; ++i){
    int r = i * 4 + r4;
    t[r][c] = Wl[(size_t)(k0 + r) * NQ + n0 + c];
  }
  __syncthreads();
  #pragma unroll
  for (int i = 0; i < 16; ++i){
    int r = i * 4 + r4;
    Tl[(size_t)(n0 + r) * KQ + k0 + c] = f2bf(t[c][r]);
  }
}

// ---------------- LayerNorm (fp32 in) + bf16 cast — layer 0 only -------------
__global__ __launch_bounds__(256) void ln_cast(const float* __restrict__ x,
                                               const float* __restrict__ gamma,
                                               const float* __restrict__ beta,
                                               u16* __restrict__ xn){
  const size_t row = blockIdx.x;
  const int tid = threadIdx.x;
  f32x4 xv = *(const f32x4*)(x + row * DQ + tid * 4);
  float s  = xv[0] + xv[1] + xv[2] + xv[3];
  float s2 = xv[0]*xv[0] + xv[1]*xv[1] + xv[2]*xv[2] + xv[3]*xv[3];
  #pragma unroll
  for (int off = 32; off > 0; off >>= 1){
    s  += __shfl_down(s,  off);
    s2 += __shfl_down(s2, off);
  }
  __shared__ float red[8];
  const int wave = tid >> 6, lane = tid & 63;
  if (lane == 0){ red[wave] = s; red[4 + wave] = s2; }
  __syncthreads();
  s  = red[0] + red[1] + red[2] + red[3];
  s2 = red[4] + red[5] + red[6] + red[7];
  const float mean = s * (1.f / DQ);
  float var = fmaxf(s2 * (1.f / DQ) - mean * mean, 0.f);
  const float rstd = rsqrtf(var + 1e-5f);
  f32x4 gv = *(const f32x4*)(gamma + tid * 4);
  f32x4 bv = *(const f32x4*)(beta  + tid * 4);
  u16x4 o;
  #pragma unroll
  for (int e = 0; e < 4; ++e) o[e] = f2bf((xv[e] - mean) * rstd * gv[e] + bv[e]);
  *(u16x4*)(xn + row * DQ + tid * 4) = o;
}

// ---------------- GEMM + fused gate math + chunk-aggregate epilogue ----------
// R7: read-ahead pipeline. R6 cycle model: per CU per K-tile, MFMA 2484 cyc
// and LDS-pipe ~2800 cyc were SERIALIZED by {BAR; reads; lgkmcnt(0); MFMA}.
// Now phase k's operands are read during phase k-1 (both LDS buffers are
// tile-stable), no hard lgkmcnt (plain loads -> compiler emits counted
// lgkmcnt, current phase's reads stay in flight through the MFMA), and
// sched_barrier(0) pins stage/read issue before each MFMA cluster.
// Ledger (2 vm-insts per STAGE; vmcnt BEFORE BAR = collective drain):
//  P1: vmcnt(2),BAR [B1(t) landed]   | stage B0(t+1) | rd bf1<-B1(pb)  | MM(0,0)
//  P2: vmcnt(2),BAR [A1(t) landed]   | stage A0(t+1) | rd afrB<-A1(pb) | MM(0,1)
//  P3: no barrier                    | stage B1(t+1) |                 | MM(1,0)
//  P4: vmcnt(2),BAR [B0,A0(t+1) ok]  | stage A1(t+1) | rd afrA,bf0<-qb | MM(1,1)
// Tail: t=NT-1: P2 vmcnt(0); P4 skips its wait/stage/read block.
// WAR: every staged region's last reader is >=3 barriers earlier (checked
// region-by-region); reads from qb at P4 touch only hf0 regions, disjoint
// from in-flight hf1 writes.
__global__ __launch_bounds__(512, 2) void gemm_k8(const u16* __restrict__ A,
                                                  const u16* __restrict__ Bt,
                                                  const float* __restrict__ bias,
                                                  u32* __restrict__ abv,
                                                  float* __restrict__ pq){
  __shared__ u16 lds[2][2][2][8192];   // [buf][op][half][row*64+col] = 128 KiB
  const int bid = blockIdx.x;
  const int swz = ((bid & 7) << 7) | (bid >> 3);   // 1024 wgs, %8==0 -> bijective
  const int bn = swz & 7, bm = swz >> 3;           // XCD owns contiguous bm stripe
  const int m0 = bm << 8;
  const int tid = threadIdx.x;
  const int w = tid >> 6, lane = tid & 63;
  const int wr = w >> 2, wc = w & 3;               // 2M x 4N wave grid
  const int lr = lane & 15, hi = lane >> 4;
  const int sl8 = lane >> 3;                       // staging row-in-8 (== row&7)
  const int sslot = (lane & 7) ^ sl8;              // pre-swizzled global slot

  f32x4 acc[2][2][4][2] = {};                      // [qm][qn=gate/hid][i][j]
  bf16x8 afrA[4][2], afrB[4][2];                   // A half0 / half1 reg sets
  bf16x8 bf0[2][2], bf1[2][2];                     // B gate/hid frags

#define FENCE asm volatile("" ::: "memory")
#define BAR do { FENCE; __builtin_amdgcn_s_barrier(); FENCE; } while(0)
#define SB  __builtin_amdgcn_sched_barrier(0)

#define STAGE(op, hf, kt, pb_) do {                                            \
    const u16* gsrc_ = (op) ? Bt : A;                                          \
    const int rb_ = (op) ? ((bn << 7) + (hf) * 1024) : (m0 + ((hf) << 7));     \
    _Pragma("unroll")                                                          \
    for (int g_ = 0; g_ < 2; ++g_){                                            \
      const int row_ = (w << 4) + (g_ << 3) + sl8;                             \
      gload_lds16(gsrc_ + (size_t)(rb_ + row_) * KQ + ((kt) << 6) + (sslot << 3),\
                  &lds[pb_][op][hf][((w << 4) + (g_ << 3)) << 6]);             \
    }                                                                          \
  } while(0)

  // swizzled ds_read: logical (row, 16B-slot) -> byte row*128 + (slot^(row&7))*16
#define LDSRD(dst, base_, row_, slot_) do {                                    \
    const int r_ = (row_);                                                     \
    dst = *(const bf16x8*)((const char*)(base_) +                              \
          ((r_ << 7) + ((((slot_)) ^ (r_ & 7)) << 4)));                        \
  } while(0)

#define RD_A(dst, hf, buf_) do {                                               \
    const u16* Ah_ = &lds[buf_][0][hf][0];                                     \
    _Pragma("unroll")                                                          \
    for (int i_ = 0; i_ < 4; ++i_)                                             \
      _Pragma("unroll")                                                        \
      for (int kk_ = 0; kk_ < 2; ++kk_)                                        \
        LDSRD(dst[i_][kk_], Ah_, (wr << 6) + (i_ << 4) + lr, (kk_ << 2) + hi); \
  } while(0)

#define RD_B(dst, hf, buf_) do {                                               \
    const u16* Bh_ = &lds[buf_][1][hf][0];                                     \
    _Pragma("unroll")                                                          \
    for (int j_ = 0; j_ < 2; ++j_)                                             \
      _Pragma("unroll")                                                        \
      for (int kk_ = 0; kk_ < 2; ++kk_)                                        \
        LDSRD(dst[j_][kk_], Bh_, (wc << 5) + (j_ << 4) + lr, (kk_ << 2) + hi); \
  } while(0)

#define MM(qm, qn, AR, B) do {                                                 \
    SB;                                                                        \
    __builtin_amdgcn_s_setprio(1);                                             \
    _Pragma("unroll")                                                          \
    for (int i_ = 0; i_ < 4; ++i_)                                             \
      _Pragma("unroll")                                                        \
      for (int j_ = 0; j_ < 2; ++j_)                                           \
        _Pragma("unroll")                                                      \
        for (int kk_ = 0; kk_ < 2; ++kk_)                                      \
          acc[qm][qn][i_][j_] = __builtin_amdgcn_mfma_f32_16x16x32_bf16(       \
              AR[i_][kk_], B[j_][kk_], acc[qm][qn][i_][j_], 0, 0, 0);          \
    __builtin_amdgcn_s_setprio(0);                                             \
  } while(0)

  // prologue: stage tile0 (order B0,A0,B1,A1); collective drain of B0,A0;
  // preload P1(0) operands.
  STAGE(1, 0, 0, 0); STAGE(0, 0, 0, 0); STAGE(1, 1, 0, 0); STAGE(0, 1, 0, 0);
  asm volatile("s_waitcnt vmcnt(4)" ::: "memory");
  BAR;
  RD_A(afrA, 0, 0); RD_B(bf0, 0, 0);

  for (int t = 0; t < NT; ++t){
    const int pb = t & 1, qb = pb ^ 1;
    const bool s = (t + 1 < NT);
    // P1
    asm volatile("s_waitcnt vmcnt(2)" ::: "memory");
    BAR;
    if (s) STAGE(1, 0, t + 1, qb);          // B0(t+1)
    RD_B(bf1, 1, pb);                       // operands for P2
    MM(0, 0, afrA, bf0);
    // P2
    if (s) { asm volatile("s_waitcnt vmcnt(2)" ::: "memory"); }
    else   { asm volatile("s_waitcnt vmcnt(0)" ::: "memory"); }
    BAR;
    if (s) STAGE(0, 0, t + 1, qb);          // A0(t+1)
    RD_A(afrB, 1, pb);                      // operands for P3
    MM(0, 1, afrA, bf1);
    // P3 (no barrier: MFMA reads regs only; staged region's readers are
    // >=2 barriers away on both sides)
    if (s) STAGE(1, 1, t + 1, qb);          // B1(t+1)
    MM(1, 0, afrB, bf0);
    // P4
    if (s){
      asm volatile("s_waitcnt vmcnt(2)" ::: "memory");
      BAR;
      STAGE(0, 1, t + 1, qb);               // A1(t+1)
      RD_A(afrA, 0, qb); RD_B(bf0, 0, qb);  // operands for P1(t+1)
    }
    MM(1, 1, afrB, bf1);
  }
#undef MM
#undef RD_B
#undef RD_A
#undef LDSRD
#undef STAGE
#undef SB

  // ---- fused epilogue: gate math + packed store + chunk (P,Q) aggregates ----
  const int dbase = (bn << 7) + (wc << 5) + lr;
  #pragma unroll
  for (int qm = 0; qm < 2; ++qm){
    const int row00 = m0 + (qm << 7) + (wr << 6);    // chunk base row
    float chP[2] = {1.f, 1.f}, chQ[2] = {0.f, 0.f};
    #pragma unroll
    for (int i = 0; i < 4; ++i){
      float sgP[2] = {1.f, 1.f}, sgQ[2] = {0.f, 0.f};
      #pragma unroll
      for (int r = 0; r < 4; ++r){
        const int row = row00 + (i << 4) + (hi << 2) + r;
        #pragma unroll
        for (int j = 0; j < 2; ++j){
          const int d = dbase + (j << 4);
          float gate = acc[qm][0][i][j][r] + bias[d];
          float hid  = acc[qm][1][i][j][r] + bias[1024 + d];
          float a, bv; sig_ab(gate, hid, a, bv);
          const u16 ua = f2bf(a), ub = f2bf(bv);
          abv[(size_t)row * 1024 + d] = (u32)ua | ((u32)ub << 16);
          const float ar = bf2f(ua), br = bf2f(ub);   // rounded (match replay)
          sgQ[j] = ar * sgQ[j] + br;                  // t ascending within seg
          sgP[j] *= ar;
        }
      }
      // ordered scan across hi-groups (lanes lr, lr+16, lr+32, lr+48)
      #pragma unroll
      for (int j = 0; j < 2; ++j){
        float p = sgP[j], q = sgQ[j];
        float p1 = __shfl_up(p, 16), q1 = __shfl_up(q, 16);
        if (hi >= 1){ q = p * q1 + q; p = p * p1; }
        float p2 = __shfl_up(p, 32), q2 = __shfl_up(q, 32);
        if (hi >= 2){ q = p * q2 + q; p = p * p2; }
        chQ[j] = p * chQ[j] + q;                      // compose i ascending
        chP[j] = p * chP[j];
      }
    }
    if (hi == 3){                                     // lane holds full chunk
      const int bq = row00 >> 12, cq = (row00 >> 6) & 63;
      #pragma unroll
      for (int j = 0; j < 2; ++j){
        const int d = dbase + (j << 4);
        f32x2 v; v[0] = chP[j]; v[1] = chQ[j];
        *(f32x2*)(pq + ((((size_t)(bq * CCH + cq)) << 10) + d) * 2) = v;
      }
    }
  }
#undef BAR
#undef FENCE
}

// ---------------- scan phase 2: scan across chunks; also emits h_last --------
__global__ __launch_bounds__(256) void scan2(const float* __restrict__ pq,
                                             float* __restrict__ hst,
                                             float* __restrict__ hlast){
  const int idx = blockIdx.x * 256 + threadIdx.x;   // 0..B*D-1
  const int b = idx >> 10, d = idx & 1023;
  float h = 0.5f;                                   // h0 = g(0) = 0.5
  for (int c = 0; c < CCH; ++c){
    const size_t o = ((size_t)(b * CCH + c) << 10) + d;
    hst[o] = h;
    f32x2 v = *(const f32x2*)(pq + o * 2);
    h = v[0] * h + v[1];
  }
  hlast[idx] = h;
}

// ---------------- scan phase 3 (fused): replay + residual [+ LN + cast] ------
// MODE 0: inp fp32 (= x), writes out bf16 + xn = LN(out) bf16  (layer 0)
// MODE 1: inp bf16,       writes out bf16 + xn = LN(out) bf16  (layer 1)
// MODE 2: inp bf16,       writes out fp32, no xn               (layer 2)
// Reads packed (a,bv) bf16 pairs — no exp in the replay loop.
template<int MODE>
__global__ __launch_bounds__(256) void scan3f(const u32* __restrict__ abv,
                                              const float* __restrict__ hst,
                                              const void* __restrict__ inp,
                                              void* __restrict__ outp,
                                              u16* __restrict__ xn,
                                              const float* __restrict__ gamma,
                                              const float* __restrict__ beta){
  const int b = blockIdx.x >> 6;
  const int c = blockIdx.x & 63;
  const int tid = threadIdx.x;
  const int d4 = tid << 2;
  const int wave = tid >> 6, lane = tid & 63;
  const size_t srow = (size_t)(b * SQ + c * TCH);
  const u32* base = abv + srow * 1024 + d4;
  const size_t o = ((size_t)blockIdx.x << 10) + d4;
  f32x4 h0v = *(const f32x4*)(hst + o);
  float h[4] = {h0v[0], h0v[1], h0v[2], h0v[3]};
  __shared__ float red[2][8];
  f32x4 gv = {}, bvv = {};
  if (MODE != 2){
    gv  = *(const f32x4*)(gamma + d4);
    bvv = *(const f32x4*)(beta  + d4);
  }
  for (int t = 0; t < TCH; ++t){
    u32x4 ab = *(const u32x4*)(base + (size_t)t * 1024);
    f32x4 iv;
    if (MODE == 0){
      iv = *(const f32x4*)((const float*)inp + (srow + t) * DQ + d4);
    } else {
      u16x4 ib = *(const u16x4*)((const u16*)inp + (srow + t) * DQ + d4);
      #pragma unroll
      for (int e = 0; e < 4; ++e) iv[e] = bf2f(ib[e]);
    }
    f32x4 ov;
    #pragma unroll
    for (int e = 0; e < 4; ++e){
      const float a  = bf2f((u16)(ab[e] & 0xffffu));
      const float bv = bf2f((u16)(ab[e] >> 16));
      h[e] = a * h[e] + bv;
      ov[e] = h[e] + iv[e];
    }
    if (MODE == 2){
      *(f32x4*)((float*)outp + (srow + t) * DQ + d4) = ov;
    } else {
      u16x4 ob;
      #pragma unroll
      for (int e = 0; e < 4; ++e) ob[e] = f2bf(ov[e]);
      *(u16x4*)((u16*)outp + (srow + t) * DQ + d4) = ob;
      // row LayerNorm (256 threads hold the whole row)
      float s  = ov[0] + ov[1] + ov[2] + ov[3];
      float s2 = ov[0]*ov[0] + ov[1]*ov[1] + ov[2]*ov[2] + ov[3]*ov[3];
      #pragma unroll
      for (int off = 32; off > 0; off >>= 1){
        s  += __shfl_down(s,  off);
        s2 += __shfl_down(s2, off);
      }
      const int rb = t & 1;
      if (lane == 0){ red[rb][wave] = s; red[rb][4 + wave] = s2; }
      __syncthreads();
      s  = red[rb][0] + red[rb][1] + red[rb][2] + red[rb][3];
      s2 = red[rb][4] + red[rb][5] + red[rb][6] + red[rb][7];
      const float mean = s * (1.f / DQ);
      float var = fmaxf(s2 * (1.f / DQ) - mean * mean, 0.f);
      const float rstd = rsqrtf(var + 1e-5f);
      u16x4 xo;
      #pragma unroll
      for (int e = 0; e < 4; ++e)
        xo[e] = f2bf((ov[e] - mean) * rstd * gv[e] + bvv[e]);
      *(u16x4*)(xn + (srow + t) * DQ + d4) = xo;
    }
  }
}

extern "C" void kernel_launch(void* const* d_in, const int* in_sizes, int n_in,
                              void* d_out, int out_size, void* d_ws, size_t ws_size,
                              hipStream_t stream) {
  const float* x     = (const float*)d_in[0];   // (8,4096,1024)
  const float* gamma = (const float*)d_in[1];   // (3,1024)
  const float* beta  = (const float*)d_in[2];   // (3,1024)
  const float* W     = (const float*)d_in[3];   // (3,1024,2048)
  const float* bias  = (const float*)d_in[4];   // (3,2048)
  float* out = (float*)d_out;                   // 33554432 + 3*8192 floats

  char* ws = (char*)d_ws;
  const size_t ACT = (size_t)MQ * DQ * 4;                 // 128 MiB region each
  u16*   bufA = (u16*)(ws);                               // bf16 out of layer 0
  u16*   bufB = (u16*)(ws + ACT);                         // bf16 out of layer 1
  u32*   abv  = (u32*)(ws + 2 * ACT);                     // MQ*1024 u32 = 128 MiB
  u16*   xn   = (u16*)(ws + 3 * ACT);                     // MQ*DQ bf16 = 64 MiB
  u16*   WT   = (u16*)(ws + 3 * ACT + (size_t)MQ * DQ * 2);
  float* pq   = (float*)(ws + 3 * ACT + (size_t)MQ * DQ * 2 + (size_t)3 * NQ * KQ * 2);
  float* hst  = pq + (size_t)2 * BQ * CCH * DQ;           // after 4 MiB pq

  wt_cast<<<dim3(KQ / 64, NQ / 64, 3), 256, 0, stream>>>(W, WT);

  const dim3 ggrid((NQ / 256) * (MQ / 256));
  // ---- layer 0 ----
  ln_cast<<<MQ, 256, 0, stream>>>(x, gamma, beta, xn);
  gemm_k8<<<ggrid, 512, 0, stream>>>(xn, WT, bias, abv, pq);
  scan2<<<(BQ * DQ) / 256, 256, 0, stream>>>(pq, hst, out + (size_t)MQ * DQ);
  scan3f<0><<<BQ * CCH, 256, 0, stream>>>(abv, hst, x, bufA, xn,
                                          gamma + DQ, beta + DQ);
  // ---- layer 1 ----
  gemm_k8<<<ggrid, 512, 0, stream>>>(xn, WT + (size_t)NQ * KQ, bias + NQ,
                                     abv, pq);
  scan2<<<(BQ * DQ) / 256, 256, 0, stream>>>(pq, hst,
                                             out + (size_t)MQ * DQ + BQ * DQ);
  scan3f<1><<<BQ * CCH, 256, 0, stream>>>(abv, hst, bufA, bufB, xn,
                                          gamma + 2 * DQ, beta + 2 * DQ);
  // ---- layer 2 ----
  gemm_k8<<<ggrid, 512, 0, stream>>>(xn, WT + (size_t)2 * NQ * KQ, bias + 2 * NQ,
                                     abv, pq);
  scan2<<<(BQ * DQ) / 256, 256, 0, stream>>>(pq, hst,
                                             out + (size_t)MQ * DQ + 2 * BQ * DQ);
  scan3f<2><<<BQ * CCH, 256, 0, stream>>>(abv, hst, bufB, out, nullptr,
                                          nullptr, nullptr);
}

// Round 8
// 716.052 us; speedup vs baseline: 1.0422x; 1.0422x over previous
//
#include <hip/hip_runtime.h>

typedef unsigned short u16;
typedef unsigned int   u32;
typedef float  f32x2  __attribute__((ext_vector_type(2)));
typedef float  f32x4  __attribute__((ext_vector_type(4)));
typedef short  bf16x8 __attribute__((ext_vector_type(8)));
typedef u16    u16x4  __attribute__((ext_vector_type(4)));
typedef u32    u32x4  __attribute__((ext_vector_type(4)));

#define BQ 8
#define SQ 4096
#define DQ 1024
#define NQ 2048      // 2*D
#define MQ 32768     // B*S
#define KQ 1024
#define CCH 128      // chunks per sequence (R8: was 64)
#define TCH 32       // timesteps per chunk (CCH*TCH == SQ)
#define NT 16        // K-tiles (KQ/64)

__device__ __forceinline__ float bf2f(u16 u){
  union { u32 i; float f; } v; v.i = ((u32)u) << 16; return v.f;
}
__device__ __forceinline__ u16 f2bf(float f){
  union { float f; u32 i; } v; v.f = f;
  u32 r = v.i + 0x7fffu + ((v.i >> 16) & 1u);   // round-to-nearest-even
  return (u16)(r >> 16);
}

// a = 1 - sigmoid(gate) = sigmoid(-gate);  bv = sigmoid(gate) * g(hidden)
__device__ __forceinline__ void sig_ab(float gate, float hid, float& a, float& bv){
  float eg = __expf(gate);
  float a_ = __builtin_amdgcn_rcpf(1.f + eg);
  float z  = 1.f - a_;
  float eh = __expf(hid);
  float sg = eh * __builtin_amdgcn_rcpf(1.f + eh);
  float gval = (hid >= 0.f) ? (hid + 0.5f) : sg;
  a = a_; bv = z * gval;
}

__device__ __forceinline__ void gload_lds16(const u16* g, u16* l){
  __builtin_amdgcn_global_load_lds(
      (const __attribute__((address_space(1))) u32*)g,
      (__attribute__((address_space(3)))       u32*)l,
      16, 0, 0);
}

// ---------------- W transpose + bf16 cast: [L][K][N] f32 -> [L][N][K] bf16 ----
__global__ __launch_bounds__(256) void wt_cast(const float* __restrict__ W,
                                               u16* __restrict__ WT){
  __shared__ float t[64][65];
  const int l  = blockIdx.z;
  const int k0 = blockIdx.x << 6, n0 = blockIdx.y << 6;
  const float* Wl = W  + (size_t)l * KQ * NQ;
  u16*         Tl = WT + (size_t)l * NQ * KQ;
  const int c = threadIdx.x & 63, r4 = threadIdx.x >> 6;
  #pragma unroll
  for (int i = 0; i < 16; ++i){
    int r = i * 4 + r4;
    t[r][c] = Wl[(size_t)(k0 + r) * NQ + n0 + c];
  }
  __syncthreads();
  #pragma unroll
  for (int i = 0; i < 16; ++i){
    int r = i * 4 + r4;
    Tl[(size_t)(n0 + r) * KQ + k0 + c] = f2bf(t[c][r]);
  }
}

// ---------------- LayerNorm (fp32 in) + bf16 cast — layer 0 only -------------
__global__ __launch_bounds__(256) void ln_cast(const float* __restrict__ x,
                                               const float* __restrict__ gamma,
                                               const float* __restrict__ beta,
                                               u16* __restrict__ xn){
  const size_t row = blockIdx.x;
  const int tid = threadIdx.x;
  f32x4 xv = *(const f32x4*)(x + row * DQ + tid * 4);
  float s  = xv[0] + xv[1] + xv[2] + xv[3];
  float s2 = xv[0]*xv[0] + xv[1]*xv[1] + xv[2]*xv[2] + xv[3]*xv[3];
  #pragma unroll
  for (int off = 32; off > 0; off >>= 1){
    s  += __shfl_down(s,  off);
    s2 += __shfl_down(s2, off);
  }
  __shared__ float red[8];
  const int wave = tid >> 6, lane = tid & 63;
  if (lane == 0){ red[wave] = s; red[4 + wave] = s2; }
  __syncthreads();
  s  = red[0] + red[1] + red[2] + red[3];
  s2 = red[4] + red[5] + red[6] + red[7];
  const float mean = s * (1.f / DQ);
  float var = fmaxf(s2 * (1.f / DQ) - mean * mean, 0.f);
  const float rstd = rsqrtf(var + 1e-5f);
  f32x4 gv = *(const f32x4*)(gamma + tid * 4);
  f32x4 bv = *(const f32x4*)(beta  + tid * 4);
  u16x4 o;
  #pragma unroll
  for (int e = 0; e < 4; ++e) o[e] = f2bf((xv[e] - mean) * rstd * gv[e] + bv[e]);
  *(u16x4*)(xn + row * DQ + tid * 4) = o;
}

// ---------------- GEMM + fused gate math + chunk-aggregate epilogue ----------
// K-loop: R7 read-ahead pipeline (ledger in R7 comments, unchanged).
// R8 changes:
//  (a) MM: kk loop OUTERMOST — R7's kk-innermost put dependent MFMAs (same
//      acc reg) back-to-back; 8 dependent pairs/cluster stall the matrix
//      pipe at 2 waves/SIMD. Now all 8 (i,j) MFMAs of kk=0 are independent,
//      and each kk=1 MFMA is 8 issues away from its kk=0 producer.
//  (b) epilogue pack via v_cvt_pk_bf16_f32 (1 inst -> packed (a|bv<<16)
//      dword, exactly the abv format; rounded floats recovered with 1 shl +
//      1 and). Replaces ~13 VALU/elem-pair; R6->R7 VALUBusy says the scalar
//      path cost ~19 us/dispatch.
//  (c) chunk = 32 rows (TCH=32, CCH=128): i-compose split into two halves,
//      two (P,Q) aggregates per 64-row band -> doubles scan3f parallelism.
__global__ __launch_bounds__(512, 2) void gemm_k8(const u16* __restrict__ A,
                                                  const u16* __restrict__ Bt,
                                                  const float* __restrict__ bias,
                                                  u32* __restrict__ abv,
                                                  float* __restrict__ pq){
  __shared__ u16 lds[2][2][2][8192];   // [buf][op][half][row*64+col] = 128 KiB
  const int bid = blockIdx.x;
  const int swz = ((bid & 7) << 7) | (bid >> 3);   // 1024 wgs, %8==0 -> bijective
  const int bn = swz & 7, bm = swz >> 3;           // XCD owns contiguous bm stripe
  const int m0 = bm << 8;
  const int tid = threadIdx.x;
  const int w = tid >> 6, lane = tid & 63;
  const int wr = w >> 2, wc = w & 3;               // 2M x 4N wave grid
  const int lr = lane & 15, hi = lane >> 4;
  const int sl8 = lane >> 3;                       // staging row-in-8 (== row&7)
  const int sslot = (lane & 7) ^ sl8;              // pre-swizzled global slot

  f32x4 acc[2][2][4][2] = {};                      // [qm][qn=gate/hid][i][j]
  bf16x8 afrA[4][2], afrB[4][2];                   // A half0 / half1 reg sets
  bf16x8 bf0[2][2], bf1[2][2];                     // B gate/hid frags

#define FENCE asm volatile("" ::: "memory")
#define BAR do { FENCE; __builtin_amdgcn_s_barrier(); FENCE; } while(0)
#define SB  __builtin_amdgcn_sched_barrier(0)

#define STAGE(op, hf, kt, pb_) do {                                            \
    const u16* gsrc_ = (op) ? Bt : A;                                          \
    const int rb_ = (op) ? ((bn << 7) + (hf) * 1024) : (m0 + ((hf) << 7));     \
    _Pragma("unroll")                                                          \
    for (int g_ = 0; g_ < 2; ++g_){                                            \
      const int row_ = (w << 4) + (g_ << 3) + sl8;                             \
      gload_lds16(gsrc_ + (size_t)(rb_ + row_) * KQ + ((kt) << 6) + (sslot << 3),\
                  &lds[pb_][op][hf][((w << 4) + (g_ << 3)) << 6]);             \
    }                                                                          \
  } while(0)

  // swizzled ds_read: logical (row, 16B-slot) -> byte row*128 + (slot^(row&7))*16
#define LDSRD(dst, base_, row_, slot_) do {                                    \
    const int r_ = (row_);                                                     \
    dst = *(const bf16x8*)((const char*)(base_) +                              \
          ((r_ << 7) + ((((slot_)) ^ (r_ & 7)) << 4)));                        \
  } while(0)

#define RD_A(dst, hf, buf_) do {                                               \
    const u16* Ah_ = &lds[buf_][0][hf][0];                                     \
    _Pragma("unroll")                                                          \
    for (int i_ = 0; i_ < 4; ++i_)                                             \
      _Pragma("unroll")                                                        \
      for (int kk_ = 0; kk_ < 2; ++kk_)                                        \
        LDSRD(dst[i_][kk_], Ah_, (wr << 6) + (i_ << 4) + lr, (kk_ << 2) + hi); \
  } while(0)

#define RD_B(dst, hf, buf_) do {                                               \
    const u16* Bh_ = &lds[buf_][1][hf][0];                                     \
    _Pragma("unroll")                                                          \
    for (int j_ = 0; j_ < 2; ++j_)                                             \
      _Pragma("unroll")                                                        \
      for (int kk_ = 0; kk_ < 2; ++kk_)                                        \
        LDSRD(dst[j_][kk_], Bh_, (wc << 5) + (j_ << 4) + lr, (kk_ << 2) + hi); \
  } while(0)

#define MM(qm, qn, AR, B) do {                                                 \
    SB;                                                                        \
    __builtin_amdgcn_s_setprio(1);                                             \
    _Pragma("unroll")                                                          \
    for (int kk_ = 0; kk_ < 2; ++kk_)                                          \
      _Pragma("unroll")                                                        \
      for (int i_ = 0; i_ < 4; ++i_)                                           \
        _Pragma("unroll")                                                      \
        for (int j_ = 0; j_ < 2; ++j_)                                         \
          acc[qm][qn][i_][j_] = __builtin_amdgcn_mfma_f32_16x16x32_bf16(       \
              AR[i_][kk_], B[j_][kk_], acc[qm][qn][i_][j_], 0, 0, 0);          \
    __builtin_amdgcn_s_setprio(0);                                             \
  } while(0)

  // prologue: stage tile0 (order B0,A0,B1,A1); collective drain of B0,A0;
  // preload P1(0) operands.
  STAGE(1, 0, 0, 0); STAGE(0, 0, 0, 0); STAGE(1, 1, 0, 0); STAGE(0, 1, 0, 0);
  asm volatile("s_waitcnt vmcnt(4)" ::: "memory");
  BAR;
  RD_A(afrA, 0, 0); RD_B(bf0, 0, 0);

  for (int t = 0; t < NT; ++t){
    const int pb = t & 1, qb = pb ^ 1;
    const bool s = (t + 1 < NT);
    // P1
    asm volatile("s_waitcnt vmcnt(2)" ::: "memory");
    BAR;
    if (s) STAGE(1, 0, t + 1, qb);          // B0(t+1)
    RD_B(bf1, 1, pb);                       // operands for P2
    MM(0, 0, afrA, bf0);
    // P2
    if (s) { asm volatile("s_waitcnt vmcnt(2)" ::: "memory"); }
    else   { asm volatile("s_waitcnt vmcnt(0)" ::: "memory"); }
    BAR;
    if (s) STAGE(0, 0, t + 1, qb);          // A0(t+1)
    RD_A(afrB, 1, pb);                      // operands for P3
    MM(0, 1, afrA, bf1);
    // P3 (no barrier: MFMA reads regs only; staged region's readers are
    // >=2 barriers away on both sides)
    if (s) STAGE(1, 1, t + 1, qb);          // B1(t+1)
    MM(1, 0, afrB, bf0);
    // P4
    if (s){
      asm volatile("s_waitcnt vmcnt(2)" ::: "memory");
      BAR;
      STAGE(0, 1, t + 1, qb);               // A1(t+1)
      RD_A(afrA, 0, qb); RD_B(bf0, 0, qb);  // operands for P1(t+1)
    }
    MM(1, 1, afrB, bf1);
  }
#undef MM
#undef RD_B
#undef RD_A
#undef LDSRD
#undef STAGE
#undef SB

  // ---- fused epilogue: gate math + packed store + chunk (P,Q) aggregates ----
  // chunk = 32 rows; i-halves {0,1} and {2,3} of each 64-row band are
  // separate chunks (row = i*16 + hi*4 + r -> half h covers rows h*32..h*32+31)
  const int dbase = (bn << 7) + (wc << 5) + lr;
  #pragma unroll
  for (int qm = 0; qm < 2; ++qm){
    const int row00 = m0 + (qm << 7) + (wr << 6);    // band base row
    #pragma unroll
    for (int half = 0; half < 2; ++half){
      float chP[2] = {1.f, 1.f}, chQ[2] = {0.f, 0.f};
      #pragma unroll
      for (int ii = 0; ii < 2; ++ii){
        const int i = (half << 1) + ii;
        float sgP[2] = {1.f, 1.f}, sgQ[2] = {0.f, 0.f};
        #pragma unroll
        for (int r = 0; r < 4; ++r){
          const int row = row00 + (i << 4) + (hi << 2) + r;
          #pragma unroll
          for (int j = 0; j < 2; ++j){
            const int d = dbase + (j << 4);
            float gate = acc[qm][0][i][j][r] + bias[d];
            float hid  = acc[qm][1][i][j][r] + bias[1024 + d];
            float a, bv; sig_ab(gate, hid, a, bv);
            u32 pk;
            asm volatile("v_cvt_pk_bf16_f32 %0, %1, %2"
                         : "=v"(pk) : "v"(a), "v"(bv));
            abv[(size_t)row * 1024 + d] = pk;
            union { u32 u; float f; } ua, ub;        // rounded (match replay)
            ua.u = pk << 16; ub.u = pk & 0xffff0000u;
            sgQ[j] = ua.f * sgQ[j] + ub.f;           // t ascending within seg
            sgP[j] *= ua.f;
          }
        }
        // ordered scan across hi-groups (lanes lr, lr+16, lr+32, lr+48)
        #pragma unroll
        for (int j = 0; j < 2; ++j){
          float p = sgP[j], q = sgQ[j];
          float p1 = __shfl_up(p, 16), q1 = __shfl_up(q, 16);
          if (hi >= 1){ q = p * q1 + q; p = p * p1; }
          float p2 = __shfl_up(p, 32), q2 = __shfl_up(q, 32);
          if (hi >= 2){ q = p * q2 + q; p = p * p2; }
          chQ[j] = p * chQ[j] + q;                   // compose ii ascending
          chP[j] = p * chP[j];
        }
      }
      if (hi == 3){                                  // lane holds full chunk
        const int rowb = row00 + (half << 5);
        const int bq = rowb >> 12, cq = (rowb >> 5) & (CCH - 1);
        #pragma unroll
        for (int j = 0; j < 2; ++j){
          const int d = dbase + (j << 4);
          f32x2 v; v[0] = chP[j]; v[1] = chQ[j];
          *(f32x2*)(pq + ((((size_t)(bq * CCH + cq)) << 10) + d) * 2) = v;
        }
      }
    }
  }
#undef BAR
#undef FENCE
}

// ---------------- scan phase 2: scan across chunks; also emits h_last --------
__global__ __launch_bounds__(256) void scan2(const float* __restrict__ pq,
                                             float* __restrict__ hst,
                                             float* __restrict__ hlast){
  const int idx = blockIdx.x * 256 + threadIdx.x;   // 0..B*D-1
  const int b = idx >> 10, d = idx & 1023;
  float h = 0.5f;                                   // h0 = g(0) = 0.5
  for (int c = 0; c < CCH; ++c){
    const size_t o = ((size_t)(b * CCH + c) << 10) + d;
    hst[o] = h;
    f32x2 v = *(const f32x2*)(pq + o * 2);
    h = v[0] * h + v[1];
  }
  hlast[idx] = h;
}

// ---------------- scan phase 3 (fused): replay + residual [+ LN + cast] ------
// MODE 0: inp fp32 (= x), writes out bf16 + xn = LN(out) bf16  (layer 0)
// MODE 1: inp bf16,       writes out bf16 + xn = LN(out) bf16  (layer 1)
// MODE 2: inp bf16,       writes out fp32, no xn               (layer 2)
// TCH=32: 1024 blocks (16 waves/CU) and half the serial depth of R7.
template<int MODE>
__global__ __launch_bounds__(256) void scan3f(const u32* __restrict__ abv,
                                              const float* __restrict__ hst,
                                              const void* __restrict__ inp,
                                              void* __restrict__ outp,
                                              u16* __restrict__ xn,
                                              const float* __restrict__ gamma,
                                              const float* __restrict__ beta){
  const int b = blockIdx.x >> 7;                    // CCH=128
  const int c = blockIdx.x & (CCH - 1);
  const int tid = threadIdx.x;
  const int d4 = tid << 2;
  const int wave = tid >> 6, lane = tid & 63;
  const size_t srow = (size_t)b * SQ + (size_t)c * TCH;
  const u32* base = abv + srow * 1024 + d4;
  const size_t o = ((size_t)blockIdx.x << 10) + d4;
  f32x4 h0v = *(const f32x4*)(hst + o);
  float h[4] = {h0v[0], h0v[1], h0v[2], h0v[3]};
  __shared__ float red[2][8];
  f32x4 gv = {}, bvv = {};
  if (MODE != 2){
    gv  = *(const f32x4*)(gamma + d4);
    bvv = *(const f32x4*)(beta  + d4);
  }
  for (int t = 0; t < TCH; ++t){
    u32x4 ab = *(const u32x4*)(base + (size_t)t * 1024);
    f32x4 iv;
    if (MODE == 0){
      iv = *(const f32x4*)((const float*)inp + (srow + t) * DQ + d4);
    } else {
      u16x4 ib = *(const u16x4*)((const u16*)inp + (srow + t) * DQ + d4);
      #pragma unroll
      for (int e = 0; e < 4; ++e) iv[e] = bf2f(ib[e]);
    }
    f32x4 ov;
    #pragma unroll
    for (int e = 0; e < 4; ++e){
      const float a  = bf2f((u16)(ab[e] & 0xffffu));
      const float bv = bf2f((u16)(ab[e] >> 16));
      h[e] = a * h[e] + bv;
      ov[e] = h[e] + iv[e];
    }
    if (MODE == 2){
      *(f32x4*)((float*)outp + (srow + t) * DQ + d4) = ov;
    } else {
      u16x4 ob;
      #pragma unroll
      for (int e = 0; e < 4; ++e) ob[e] = f2bf(ov[e]);
      *(u16x4*)((u16*)outp + (srow + t) * DQ + d4) = ob;
      // row LayerNorm (256 threads hold the whole row)
      float s  = ov[0] + ov[1] + ov[2] + ov[3];
      float s2 = ov[0]*ov[0] + ov[1]*ov[1] + ov[2]*ov[2] + ov[3]*ov[3];
      #pragma unroll
      for (int off = 32; off > 0; off >>= 1){
        s  += __shfl_down(s,  off);
        s2 += __shfl_down(s2, off);
      }
      const int rb = t & 1;
      if (lane == 0){ red[rb][wave] = s; red[rb][4 + wave] = s2; }
      __syncthreads();
      s  = red[rb][0] + red[rb][1] + red[rb][2] + red[rb][3];
      s2 = red[rb][4] + red[rb][5] + red[rb][6] + red[rb][7];
      const float mean = s * (1.f / DQ);
      float var = fmaxf(s2 * (1.f / DQ) - mean * mean, 0.f);
      const float rstd = rsqrtf(var + 1e-5f);
      u16x4 xo;
      #pragma unroll
      for (int e = 0; e < 4; ++e)
        xo[e] = f2bf((ov[e] - mean) * rstd * gv[e] + bvv[e]);
      *(u16x4*)(xn + (srow + t) * DQ + d4) = xo;
    }
  }
}

extern "C" void kernel_launch(void* const* d_in, const int* in_sizes, int n_in,
                              void* d_out, int out_size, void* d_ws, size_t ws_size,
                              hipStream_t stream) {
  const float* x     = (const float*)d_in[0];   // (8,4096,1024)
  const float* gamma = (const float*)d_in[1];   // (3,1024)
  const float* beta  = (const float*)d_in[2];   // (3,1024)
  const float* W     = (const float*)d_in[3];   // (3,1024,2048)
  const float* bias  = (const float*)d_in[4];   // (3,2048)
  float* out = (float*)d_out;                   // 33554432 + 3*8192 floats

  char* ws = (char*)d_ws;
  const size_t ACT = (size_t)MQ * DQ * 4;                 // 128 MiB region each
  u16*   bufA = (u16*)(ws);                               // bf16 out of layer 0
  u16*   bufB = (u16*)(ws + ACT);                         // bf16 out of layer 1
  u32*   abv  = (u32*)(ws + 2 * ACT);                     // MQ*1024 u32 = 128 MiB
  u16*   xn   = (u16*)(ws + 3 * ACT);                     // MQ*DQ bf16 = 64 MiB
  u16*   WT   = (u16*)(ws + 3 * ACT + (size_t)MQ * DQ * 2);
  float* pq   = (float*)(ws + 3 * ACT + (size_t)MQ * DQ * 2 + (size_t)3 * NQ * KQ * 2);
  float* hst  = pq + (size_t)2 * BQ * CCH * DQ;           // after 8 MiB pq

  wt_cast<<<dim3(KQ / 64, NQ / 64, 3), 256, 0, stream>>>(W, WT);

  const dim3 ggrid((NQ / 256) * (MQ / 256));
  // ---- layer 0 ----
  ln_cast<<<MQ, 256, 0, stream>>>(x, gamma, beta, xn);
  gemm_k8<<<ggrid, 512, 0, stream>>>(xn, WT, bias, abv, pq);
  scan2<<<(BQ * DQ) / 256, 256, 0, stream>>>(pq, hst, out + (size_t)MQ * DQ);
  scan3f<0><<<BQ * CCH, 256, 0, stream>>>(abv, hst, x, bufA, xn,
                                          gamma + DQ, beta + DQ);
  // ---- layer 1 ----
  gemm_k8<<<ggrid, 512, 0, stream>>>(xn, WT + (size_t)NQ * KQ, bias + NQ,
                                     abv, pq);
  scan2<<<(BQ * DQ) / 256, 256, 0, stream>>>(pq, hst,
                                             out + (size_t)MQ * DQ + BQ * DQ);
  scan3f<1><<<BQ * CCH, 256, 0, stream>>>(abv, hst, bufA, bufB, xn,
                                          gamma + 2 * DQ, beta + 2 * DQ);
  // ---- layer 2 ----
  gemm_k8<<<ggrid, 512, 0, stream>>>(xn, WT + (size_t)2 * NQ * KQ, bias + 2 * NQ,
                                     abv, pq);
  scan2<<<(BQ * DQ) / 256, 256, 0, stream>>>(pq, hst,
                                             out + (size_t)MQ * DQ + 2 * BQ * DQ);
  scan3f<2><<<BQ * CCH, 256, 0, stream>>>(abv, hst, bufB, out, nullptr,
                                          nullptr, nullptr);
}